// Round 9
// baseline (276.829 us; speedup 1.0000x reference)
//
#include <hip/hip_runtime.h>
#include <hip/hip_bf16.h>

using bf16 = __hip_bfloat16;
typedef __attribute__((ext_vector_type(8))) short bf16x8;
typedef __attribute__((ext_vector_type(4))) float f32x4;
typedef __attribute__((ext_vector_type(4))) int i32x4;

#define DECAY 0.25f

// ---------------------------------------------------------------- helpers
__device__ __forceinline__ void gload_lds16(const void* g, void* l) {
  __builtin_amdgcn_global_load_lds(
      (const __attribute__((address_space(1))) void*)g,
      (__attribute__((address_space(3))) void*)l, 16, 0, 0);
}

__device__ __forceinline__ unsigned short f2bf(float f) {
  __hip_bfloat16 h = __float2bfloat16(f);
  return *reinterpret_cast<unsigned short*>(&h);
}

// ---------------------------------------------------------------- prep kernels
__global__ void transpose_cast_k(const float* __restrict__ w, bf16* __restrict__ wt, int N) {
  __shared__ float t[32][33];
  int bx = blockIdx.x * 32, by = blockIdx.y * 32;
  int tx = threadIdx.x, ty = threadIdx.y;  // block (32,8)
#pragma unroll
  for (int i = 0; i < 32; i += 8)
    t[ty + i][tx] = w[(size_t)(by + ty + i) * N + bx + tx];
  __syncthreads();
#pragma unroll
  for (int i = 0; i < 32; i += 8)
    wt[(size_t)(bx + ty + i) * N + by + tx] = __float2bfloat16(t[tx][ty + i]);
}

// stage 1: per-(k-slab, n) partial absmax, coalesced, atomicMax on uint bits
__global__ void colmax_part_k(const float* __restrict__ w, unsigned int* __restrict__ maxbits,
                              int N, int KCH) {
  int n = blockIdx.x * blockDim.x + threadIdx.x;
  int k0 = blockIdx.y * KCH;
  float mx = 0.f;
  for (int k = k0; k < k0 + KCH; ++k) mx = fmaxf(mx, fabsf(w[(size_t)k * N + n]));
  atomicMax(&maxbits[n], __float_as_uint(mx));
}

__global__ void colmax_fin_k(const unsigned int* __restrict__ maxbits,
                             float* __restrict__ scale, float* __restrict__ inv, int N) {
  int n = blockIdx.x * blockDim.x + threadIdx.x;
  float mx = __uint_as_float(maxbits[n]);
  scale[n] = mx * (1.f / 127.f);
  inv[n] = (mx > 0.f) ? 127.f / mx : 0.f;
}

// w_out [K][N] f32 -> w_q8T [N][K] i8, per-n scaling
__global__ void transpose_quant_k(const float* __restrict__ w, const float* __restrict__ inv,
                                  signed char* __restrict__ wq, int N, int K) {
  __shared__ float t[32][33];
  int bx = blockIdx.x * 32, by = blockIdx.y * 32;  // bx: n-range, by: k-range
  int tx = threadIdx.x, ty = threadIdx.y;          // block (32,8)
#pragma unroll
  for (int i = 0; i < 32; i += 8)
    t[ty + i][tx] = w[(size_t)(by + ty + i) * N + bx + tx];
  __syncthreads();
#pragma unroll
  for (int i = 0; i < 32; i += 8) {
    int n = bx + ty + i;
    float v = t[tx][ty + i] * inv[n];
    int q = __float2int_rn(v);
    q = max(-127, min(127, q));
    wq[(size_t)n * K + by + tx] = (signed char)q;
  }
}

// ---------------------------------------------------------------- staging
// All regions are FRAGMENT-MAJOR (0 bank conflicts, verified R3):
// 32KB region = two 16KB k-sub-planes; sub-plane byte dd = f*1024 + l*16 holds
// src[row0 + f*16 + (l&15)][ksub + (l>>4)*E ..+E]  (E = 8 bf16 / 16 i8)

// bf16 region: 256 rows x 64 k, via global_load_lds
__device__ __forceinline__ void stageB_bf16(const bf16* __restrict__ src, int ldk,
                                            int row0, int k0, char* region, int tid) {
#pragma unroll
  for (int u = 0; u < 4; ++u) {
    int d = tid * 16 + u * 8192;
    int sub = d >> 14, dd = d & 16383;
    int f = dd >> 10, l = (dd >> 4) & 63;
    const bf16* g = src + (size_t)(row0 + f * 16 + (l & 15)) * ldk + k0 + sub * 32 + (l >> 4) * 8;
    gload_lds16(g, region + d);
  }
}

// i8 region: 256 rows x 128 k, via global_load_lds
__device__ __forceinline__ void stage_i8(const signed char* __restrict__ src, int ldk,
                                         int row0, int k0, char* region, int tid) {
#pragma unroll
  for (int u = 0; u < 4; ++u) {
    int d = tid * 16 + u * 8192;
    int sub = d >> 14, dd = d & 16383;
    int f = dd >> 10, l = (dd >> 4) & 63;
    const signed char* g =
        src + (size_t)(row0 + f * 16 + (l & 15)) * ldk + k0 + sub * 64 + (l >> 4) * 16;
    gload_lds16(g, region + d);
  }
}

// A from f32 x: reg-staged (load early / cvt+write late), fused f32->bf16 cast
__device__ __forceinline__ void stageA_load(const float* __restrict__ x, int ldk,
                                            int row0, int k0, int tid, float4 (&v)[4][2]) {
#pragma unroll
  for (int u = 0; u < 4; ++u) {
    int d = tid * 16 + u * 8192;
    int sub = d >> 14, dd = d & 16383;
    int f = dd >> 10, l = (dd >> 4) & 63;
    const float* g = x + (size_t)(row0 + f * 16 + (l & 15)) * ldk + k0 + sub * 32 + (l >> 4) * 8;
    v[u][0] = *(const float4*)g;
    v[u][1] = *(const float4*)(g + 4);
  }
}

__device__ __forceinline__ void stageA_write(const float4 (&v)[4][2], char* region, int tid) {
#pragma unroll
  for (int u = 0; u < 4; ++u) {
    int d = tid * 16 + u * 8192;
    bf16x8 o;
    o[0] = (short)f2bf(v[u][0].x); o[1] = (short)f2bf(v[u][0].y);
    o[2] = (short)f2bf(v[u][0].z); o[3] = (short)f2bf(v[u][0].w);
    o[4] = (short)f2bf(v[u][1].x); o[5] = (short)f2bf(v[u][1].y);
    o[6] = (short)f2bf(v[u][1].z); o[7] = (short)f2bf(v[u][1].w);
    *(bf16x8*)(region + d) = o;
  }
}

// ---------------------------------------------------------------- GEMM1: xp = bf16(x) @ w_inT + b_in
// 256x256 tile, BK=64, 8 waves (2Mx4N, per-wave 128x64), m97-style 1 barrier/tile.
// LDS buffer (64KB): A region @0 (reg-staged from f32 x), B region @32768 (gload). x2 dbuf.
__global__ __launch_bounds__(512, 1) void gemm1_bf16_k(
    const float* __restrict__ X, const bf16* __restrict__ BT,
    bf16* __restrict__ C, const float* __restrict__ bias, int M, int N, int K) {
  __shared__ char lds[131072];
  const int tid = threadIdx.x, lane = tid & 63, w = tid >> 6;
  const int wr = w >> 2, wc = w & 3;
  const int tm = blockIdx.x * 256, tn = blockIdx.y * 256;
  const int ro = lane * 16;
  const int NT = K >> 6;

  f32x4 acc[8][4] = {};

  {  // prologue: tile 0
    float4 av[4][2];
    stageA_load(X, K, tm, 0, tid, av);
    stageB_bf16(BT, K, tn, 0, lds + 32768, tid);
    stageA_write(av, lds + 0, tid);
    __syncthreads();
  }

  for (int t = 0; t < NT; ++t) {
    const char* cb = lds + (t & 1) * 65536;
    char* nb = lds + ((t + 1) & 1) * 65536;
    const bool pf = (t + 1 < NT);
    float4 av[4][2];
    if (pf) {
      stageA_load(X, K, tm, (t + 1) * 64, tid, av);     // issue early
      stageB_bf16(BT, K, tn, (t + 1) * 64, nb + 32768, tid);
    }
    {  // kh = 0
      const char* ab = cb + wr * 8192;
      const char* bb = cb + 32768 + wc * 4096;
      bf16x8 a[8], b[4];
#pragma unroll
      for (int j = 0; j < 4; ++j) b[j] = *(const bf16x8*)(bb + j * 1024 + ro);
#pragma unroll
      for (int i = 0; i < 8; ++i) a[i] = *(const bf16x8*)(ab + i * 1024 + ro);
#pragma unroll
      for (int i = 0; i < 8; ++i)
#pragma unroll
        for (int j = 0; j < 4; ++j)
          acc[i][j] = __builtin_amdgcn_mfma_f32_16x16x32_bf16(a[i], b[j], acc[i][j], 0, 0, 0);
    }
    {  // kh = 1
      const char* ab = cb + 16384 + wr * 8192;
      const char* bb = cb + 32768 + 16384 + wc * 4096;
      bf16x8 a[8], b[4];
#pragma unroll
      for (int j = 0; j < 4; ++j) b[j] = *(const bf16x8*)(bb + j * 1024 + ro);
#pragma unroll
      for (int i = 0; i < 8; ++i) a[i] = *(const bf16x8*)(ab + i * 1024 + ro);
#pragma unroll
      for (int i = 0; i < 8; ++i)
#pragma unroll
        for (int j = 0; j < 4; ++j)
          acc[i][j] = __builtin_amdgcn_mfma_f32_16x16x32_bf16(a[i], b[j], acc[i][j], 0, 0, 0);
    }
    if (pf) stageA_write(av, nb, tid);  // write late (compiler places vmcnt here)
    __syncthreads();                    // full drain: gload + ds_write published
  }

  // epilogue: C/D layout col=lane&15, row=(lane>>4)*4+r  [m89]
#pragma unroll
  for (int i = 0; i < 8; ++i) {
    int m0 = tm + wr * 128 + i * 16 + (lane >> 4) * 4;
#pragma unroll
    for (int j = 0; j < 4; ++j) {
      int n = tn + wc * 64 + j * 16 + (lane & 15);
      float bb = bias[n];
#pragma unroll
      for (int r = 0; r < 4; ++r)
        C[(size_t)(m0 + r) * N + n] = __float2bfloat16(acc[i][j][r] + bb);
    }
  }
}

// ---------------------------------------------------------------- GEMM2: out = x + alpha*(spikes @ w_q8T * scale + b_out)
// i8, 256x256 tile, BK=128 (NT=16, half the barriers), 1 barrier/tile.
// LDS buffer (64KB): A region @0, B region @32768; x2 dbuf = 128KB.
__global__ __launch_bounds__(512, 1) void gemm2_i8_k(
    const signed char* __restrict__ A, const signed char* __restrict__ BT,
    float* __restrict__ C, const float* __restrict__ scale,
    const float* __restrict__ bias, const float* __restrict__ xres,
    const float* __restrict__ alpha_p, int M, int N, int K) {
  __shared__ char lds[131072];
  const int tid = threadIdx.x, lane = tid & 63, w = tid >> 6;
  const int wr = w >> 2, wc = w & 3;
  const int tm = blockIdx.x * 256, tn = blockIdx.y * 256;
  const int ro = lane * 16;
  const int NT = K >> 7;

  i32x4 acc[8][4] = {};

  stage_i8(A,  K, tm, 0, lds + 0,     tid);
  stage_i8(BT, K, tn, 0, lds + 32768, tid);
  __syncthreads();

  for (int t = 0; t < NT; ++t) {
    const char* cb = lds + (t & 1) * 65536;
    char* nb = lds + ((t + 1) & 1) * 65536;
    if (t + 1 < NT) {
      stage_i8(A,  K, tm, (t + 1) * 128, nb + 0,     tid);
      stage_i8(BT, K, tn, (t + 1) * 128, nb + 32768, tid);
    }
#pragma unroll
    for (int kk = 0; kk < 2; ++kk) {
      const char* ab = cb + kk * 16384 + wr * 8192;
      const char* bb = cb + 32768 + kk * 16384 + wc * 4096;
      i32x4 a[8], b[4];
#pragma unroll
      for (int j = 0; j < 4; ++j) b[j] = *(const i32x4*)(bb + j * 1024 + ro);
#pragma unroll
      for (int i = 0; i < 8; ++i) a[i] = *(const i32x4*)(ab + i * 1024 + ro);
#pragma unroll
      for (int i = 0; i < 8; ++i)
#pragma unroll
        for (int j = 0; j < 4; ++j)
          acc[i][j] = __builtin_amdgcn_mfma_i32_16x16x64_i8(a[i], b[j], acc[i][j], 0, 0, 0);
    }
    __syncthreads();
  }

  // epilogue: out = x + alpha*(acc*scale[n] + b_out[n])
  float alpha = *alpha_p;
#pragma unroll
  for (int i = 0; i < 8; ++i) {
    int m0 = tm + wr * 128 + i * 16 + (lane >> 4) * 4;
#pragma unroll
    for (int j = 0; j < 4; ++j) {
      int n = tn + wc * 64 + j * 16 + (lane & 15);
      float sc = scale[n];
      float bb = bias[n];
#pragma unroll
      for (int r = 0; r < 4; ++r) {
        size_t idx = (size_t)(m0 + r) * N + n;
        C[idx] = xres[idx] + alpha * ((float)acc[i][j][r] * sc + bb);
      }
    }
  }
}

// ---------------------------------------------------------------- chunked LIF scan (bf16 in, u8 out)
__global__ void snn_scan_k(const bf16* __restrict__ xp, unsigned char* __restrict__ sp,
                           const float* __restrict__ thre_p,
                           int T, int H, int CHUNK, int WARM) {
  int h = blockIdx.x * blockDim.x + threadIdx.x;
  int b = blockIdx.y;
  int c = blockIdx.z;
  float thre = *thre_p;
  float l1 = thre, l2 = 2.f * thre, l3 = 3.f * thre, l4 = 4.f * thre;
  int t0 = c * CHUNK;
  int tw = t0 - WARM;
  if (tw < 0) tw = 0;
  const bf16* xcol = xp + (size_t)b * T * H + h;
  unsigned char* scol = sp + (size_t)b * T * H + h;
  float mem = 0.f;
  for (int t = tw; t < t0; ++t) {  // warmup (state error ~0.25^WARM)
    float xv = __bfloat162float(xcol[(size_t)t * H]);
    mem = DECAY * mem + xv;
    int s = (mem >= l1) + (mem >= l2) + (mem >= l3) + (mem >= l4);
    mem -= (float)s * thre;
  }
  for (int t = t0; t < t0 + CHUNK; ++t) {
    float xv = __bfloat162float(xcol[(size_t)t * H]);
    mem = DECAY * mem + xv;
    int s = (mem >= l1) + (mem >= l2) + (mem >= l3) + (mem >= l4);
    mem -= (float)s * thre;
    scol[(size_t)t * H] = (unsigned char)s;
  }
}

// ---------------------------------------------------------------- launch
extern "C" void kernel_launch(void* const* d_in, const int* in_sizes, int n_in,
                              void* d_out, int out_size, void* d_ws, size_t ws_size,
                              hipStream_t stream) {
  const float* x     = (const float*)d_in[0];
  const float* alpha = (const float*)d_in[1];
  const float* thre  = (const float*)d_in[2];
  const float* w_in  = (const float*)d_in[3];
  const float* b_in  = (const float*)d_in[4];
  const float* w_out = (const float*)d_in[5];
  const float* b_out = (const float*)d_in[6];
  float* out = (float*)d_out;

  const int B = 4, T = 2048, H = 2048;
  const int M = B * T;  // 8192
  const int K = H, N = H;

  char* ws = (char*)d_ws;
  size_t off = 0;
  signed char* spikes = (signed char*)(ws + off); off += (size_t)M * K;      // 16.8MB
  bf16* w_inT   = (bf16*)(ws + off);              off += (size_t)K * N * 2;  // 8.4MB
  signed char* w_q8T = (signed char*)(ws + off);  off += (size_t)K * N;      // 4.2MB
  float* qscale = (float*)(ws + off);             off += (size_t)N * 4;
  float* qinv   = (float*)(ws + off);             off += (size_t)N * 4;
  unsigned int* qmaxbits = (unsigned int*)(ws + off); off += (size_t)N * 4;
  bf16* xp      = (bf16*)(ws + off);              off += (size_t)M * K * 2;  // 33.5MB

  dim3 tb(32, 8);
  dim3 tg(N / 32, K / 32);
  transpose_cast_k<<<tg, tb, 0, stream>>>(w_in, w_inT, N);

  hipMemsetAsync(qmaxbits, 0, (size_t)N * 4, stream);
  const int KCH = 128;
  dim3 cg(N / 256, K / KCH);
  colmax_part_k<<<cg, 256, 0, stream>>>(w_out, qmaxbits, N, KCH);
  colmax_fin_k<<<N / 256, 256, 0, stream>>>(qmaxbits, qscale, qinv, N);
  transpose_quant_k<<<tg, tb, 0, stream>>>(w_out, qinv, w_q8T, N, K);

  dim3 gg(M / 256, N / 256);
  gemm1_bf16_k<<<gg, 512, 0, stream>>>(x, w_inT, xp, b_in, M, N, K);

  const int CHUNK = 128, WARM = 32, NC = T / CHUNK;
  dim3 sg(H / 256, B, NC);
  snn_scan_k<<<sg, 256, 0, stream>>>(xp, (unsigned char*)spikes, thre, T, H, CHUNK, WARM);

  gemm2_i8_k<<<gg, 512, 0, stream>>>(spikes, w_q8T, out, qscale, b_out, x, alpha, M, N, K);
}

// Round 10
// 219.018 us; speedup vs baseline: 1.2640x; 1.2640x over previous
//
#include <hip/hip_runtime.h>
#include <hip/hip_bf16.h>

using bf16 = __hip_bfloat16;
typedef __attribute__((ext_vector_type(8))) short bf16x8;
typedef __attribute__((ext_vector_type(4))) float f32x4;
typedef __attribute__((ext_vector_type(4))) int i32x4;

#define DECAY 0.25f

// ---------------------------------------------------------------- helpers
__device__ __forceinline__ void gload_lds16(const void* g, void* l) {
  __builtin_amdgcn_global_load_lds(
      (const __attribute__((address_space(1))) void*)g,
      (__attribute__((address_space(3))) void*)l, 16, 0, 0);
}

#define CFENCE() asm volatile("" ::: "memory")
#define VMCNT4() asm volatile("s_waitcnt vmcnt(4)" ::: "memory")

__device__ __forceinline__ unsigned short f2bf(float f) {
  __hip_bfloat16 h = __float2bfloat16(f);
  return *reinterpret_cast<unsigned short*>(&h);
}

// ---------------------------------------------------------------- prep kernels
__global__ void cast_x_k(const float4* __restrict__ x, ushort4* __restrict__ xb, int n4) {
  int i = blockIdx.x * blockDim.x + threadIdx.x;
  int stride = gridDim.x * blockDim.x;
  for (; i < n4; i += stride) {
    float4 v = x[i];
    ushort4 o;
    o.x = f2bf(v.x); o.y = f2bf(v.y); o.z = f2bf(v.z); o.w = f2bf(v.w);
    xb[i] = o;
  }
}

__global__ void transpose_cast_k(const float* __restrict__ w, bf16* __restrict__ wt, int N) {
  __shared__ float t[32][33];
  int bx = blockIdx.x * 32, by = blockIdx.y * 32;
  int tx = threadIdx.x, ty = threadIdx.y;  // block (32,8)
#pragma unroll
  for (int i = 0; i < 32; i += 8)
    t[ty + i][tx] = w[(size_t)(by + ty + i) * N + bx + tx];
  __syncthreads();
#pragma unroll
  for (int i = 0; i < 32; i += 8)
    wt[(size_t)(bx + ty + i) * N + by + tx] = __float2bfloat16(t[tx][ty + i]);
}

__global__ void colmax_part_k(const float* __restrict__ w, unsigned int* __restrict__ maxbits,
                              int N, int KCH) {
  int n = blockIdx.x * blockDim.x + threadIdx.x;
  int k0 = blockIdx.y * KCH;
  float mx = 0.f;
  for (int k = k0; k < k0 + KCH; ++k) mx = fmaxf(mx, fabsf(w[(size_t)k * N + n]));
  atomicMax(&maxbits[n], __float_as_uint(mx));
}

__global__ void colmax_fin_k(const unsigned int* __restrict__ maxbits,
                             float* __restrict__ scale, float* __restrict__ inv, int N) {
  int n = blockIdx.x * blockDim.x + threadIdx.x;
  float mx = __uint_as_float(maxbits[n]);
  scale[n] = mx * (1.f / 127.f);
  inv[n] = (mx > 0.f) ? 127.f / mx : 0.f;
}

__global__ void transpose_quant_k(const float* __restrict__ w, const float* __restrict__ inv,
                                  signed char* __restrict__ wq, int N, int K) {
  __shared__ float t[32][33];
  int bx = blockIdx.x * 32, by = blockIdx.y * 32;  // bx: n-range, by: k-range
  int tx = threadIdx.x, ty = threadIdx.y;          // block (32,8)
#pragma unroll
  for (int i = 0; i < 32; i += 8)
    t[ty + i][tx] = w[(size_t)(by + ty + i) * N + bx + tx];
  __syncthreads();
#pragma unroll
  for (int i = 0; i < 32; i += 8) {
    int n = bx + ty + i;
    float v = t[tx][ty + i] * inv[n];
    int q = __float2int_rn(v);
    q = max(-127, min(127, q));
    wq[(size_t)n * K + by + tx] = (signed char)q;
  }
}

// ---------------------------------------------------------------- staging (FRAGMENT-MAJOR, 0 conflicts verified R3)
// 16KB sub-plane: byte d = f*1024 + l*16 holds src[row0+f*16+(l&15)][k0+(l>>4)*E ..+E]
// bf16: E=8 (k-span 32); i8: E=16 (k-span 64). 256 rows each.
__device__ __forceinline__ void stage_bf16(const bf16* __restrict__ src, int ldk,
                                           int row0, int k0, char* plane, int tid) {
#pragma unroll
  for (int u = 0; u < 2; ++u) {
    int d = tid * 16 + u * 8192;
    int f = d >> 10;
    int l = (d >> 4) & 63;
    const bf16* g = src + (size_t)(row0 + f * 16 + (l & 15)) * ldk + k0 + (l >> 4) * 8;
    gload_lds16(g, plane + d);
  }
}

__device__ __forceinline__ void stage_i8(const signed char* __restrict__ src, int ldk,
                                         int row0, int k0, char* plane, int tid) {
#pragma unroll
  for (int u = 0; u < 2; ++u) {
    int d = tid * 16 + u * 8192;
    int f = d >> 10;
    int l = (d >> 4) & 63;
    const signed char* g = src + (size_t)(row0 + f * 16 + (l & 15)) * ldk + k0 + (l >> 4) * 16;
    gload_lds16(g, plane + d);
  }
}

// ---------------------------------------------------------------- GEMM1 "ring3": xp = bf16(x) @ w_inT + b_in
// 256x256 tile, BK=32, 8 waves (2Mx4N, per-wave 128x64), 3-buffer ring (96KB),
// one phase per K-tile: stage(t+2) -> read-once-to-regs -> 32 MFMA -> vmcnt(4) -> s_barrier.
// Ledger: RAW - tile t staged at t-2, drained (oldest-4) by vmcnt(4) at end t-1, published by barrier.
//         WAR - stage(t+2) hits buf (t-1)%3 whose reads (into regs) finished before t-1's barrier.
__global__ __launch_bounds__(512, 1) void gemm1_bf16_k(
    const bf16* __restrict__ A, const bf16* __restrict__ BT,
    bf16* __restrict__ C, const float* __restrict__ bias, int M, int N, int K) {
  __shared__ char lds[98304];
  const int tid = threadIdx.x, lane = tid & 63, w = tid >> 6;
  const int wr = w >> 2, wc = w & 3;
  const int tm = blockIdx.x * 256, tn = blockIdx.y * 256;
  const int ro = lane * 16;
  const int NT = K >> 5;  // 64

  f32x4 acc[8][4] = {};

  // prologue: t0 -> buf0, t1 -> buf1; vmcnt(4): t0 landed, t1 (4 loads) in flight
  stage_bf16(A,  K, tm, 0,  lds + 0,     tid);
  stage_bf16(BT, K, tn, 0,  lds + 16384, tid);
  stage_bf16(A,  K, tm, 32, lds + 32768 + 0,     tid);
  stage_bf16(BT, K, tn, 32, lds + 32768 + 16384, tid);
  CFENCE();
  VMCNT4();
  __builtin_amdgcn_s_barrier();

  for (int t = 0; t < NT; ++t) {
    const char* cb = lds + (t % 3) * 32768;
    char* sb = lds + ((t + 2) % 3) * 32768;
    const int k2 = (t + 2 < NT ? t + 2 : NT - 1) * 32;
    stage_bf16(A,  K, tm, k2, sb + 0,     tid);
    stage_bf16(BT, K, tn, k2, sb + 16384, tid);
    CFENCE();
    bf16x8 a[8], b[4];
#pragma unroll
    for (int j = 0; j < 4; ++j) b[j] = *(const bf16x8*)(cb + 16384 + (wc * 4 + j) * 1024 + ro);
#pragma unroll
    for (int i = 0; i < 8; ++i) a[i] = *(const bf16x8*)(cb + (wr * 8 + i) * 1024 + ro);
    __builtin_amdgcn_s_setprio(1);
#pragma unroll
    for (int i = 0; i < 8; ++i)
#pragma unroll
      for (int j = 0; j < 4; ++j)
        acc[i][j] = __builtin_amdgcn_mfma_f32_16x16x32_bf16(a[i], b[j], acc[i][j], 0, 0, 0);
    __builtin_amdgcn_s_setprio(0);
    CFENCE();
    VMCNT4();   // t+1's 4 loads landed; t+2's 4 in flight
    __builtin_amdgcn_s_barrier();
    CFENCE();
  }

  // epilogue: C/D layout col=lane&15, row=(lane>>4)*4+r  [m89]
#pragma unroll
  for (int i = 0; i < 8; ++i) {
    int m0 = tm + wr * 128 + i * 16 + (lane >> 4) * 4;
#pragma unroll
    for (int j = 0; j < 4; ++j) {
      int n = tn + wc * 64 + j * 16 + (lane & 15);
      float bb = bias[n];
#pragma unroll
      for (int r = 0; r < 4; ++r)
        C[(size_t)(m0 + r) * N + n] = __float2bfloat16(acc[i][j][r] + bb);
    }
  }
}

// ---------------------------------------------------------------- GEMM2 "ring3" i8: out = x + alpha*(spikes @ w_q8T * scale + b_out)
// Same structure, BK=64 (i8 frag spans K=64), NT=32.
__global__ __launch_bounds__(512, 1) void gemm2_i8_k(
    const signed char* __restrict__ A, const signed char* __restrict__ BT,
    float* __restrict__ C, const float* __restrict__ scale,
    const float* __restrict__ bias, const float* __restrict__ xres,
    const float* __restrict__ alpha_p, int M, int N, int K) {
  __shared__ char lds[98304];
  const int tid = threadIdx.x, lane = tid & 63, w = tid >> 6;
  const int wr = w >> 2, wc = w & 3;
  const int tm = blockIdx.x * 256, tn = blockIdx.y * 256;
  const int ro = lane * 16;
  const int NT = K >> 6;  // 32

  i32x4 acc[8][4] = {};

  stage_i8(A,  K, tm, 0,  lds + 0,     tid);
  stage_i8(BT, K, tn, 0,  lds + 16384, tid);
  stage_i8(A,  K, tm, 64, lds + 32768 + 0,     tid);
  stage_i8(BT, K, tn, 64, lds + 32768 + 16384, tid);
  CFENCE();
  VMCNT4();
  __builtin_amdgcn_s_barrier();

  for (int t = 0; t < NT; ++t) {
    const char* cb = lds + (t % 3) * 32768;
    char* sb = lds + ((t + 2) % 3) * 32768;
    const int k2 = (t + 2 < NT ? t + 2 : NT - 1) * 64;
    stage_i8(A,  K, tm, k2, sb + 0,     tid);
    stage_i8(BT, K, tn, k2, sb + 16384, tid);
    CFENCE();
    i32x4 a[8], b[4];
#pragma unroll
    for (int j = 0; j < 4; ++j) b[j] = *(const i32x4*)(cb + 16384 + (wc * 4 + j) * 1024 + ro);
#pragma unroll
    for (int i = 0; i < 8; ++i) a[i] = *(const i32x4*)(cb + (wr * 8 + i) * 1024 + ro);
    __builtin_amdgcn_s_setprio(1);
#pragma unroll
    for (int i = 0; i < 8; ++i)
#pragma unroll
      for (int j = 0; j < 4; ++j)
        acc[i][j] = __builtin_amdgcn_mfma_i32_16x16x64_i8(a[i], b[j], acc[i][j], 0, 0, 0);
    __builtin_amdgcn_s_setprio(0);
    CFENCE();
    VMCNT4();
    __builtin_amdgcn_s_barrier();
    CFENCE();
  }

  // epilogue: out = x + alpha*(acc*scale[n] + b_out[n])
  float alpha = *alpha_p;
#pragma unroll
  for (int i = 0; i < 8; ++i) {
    int m0 = tm + wr * 128 + i * 16 + (lane >> 4) * 4;
#pragma unroll
    for (int j = 0; j < 4; ++j) {
      int n = tn + wc * 64 + j * 16 + (lane & 15);
      float sc = scale[n];
      float bb = bias[n];
#pragma unroll
      for (int r = 0; r < 4; ++r) {
        size_t idx = (size_t)(m0 + r) * N + n;
        C[idx] = xres[idx] + alpha * ((float)acc[i][j][r] * sc + bb);
      }
    }
  }
}

// ---------------------------------------------------------------- chunked LIF scan (bf16 in, u8 out)
__global__ void snn_scan_k(const bf16* __restrict__ xp, unsigned char* __restrict__ sp,
                           const float* __restrict__ thre_p,
                           int T, int H, int CHUNK, int WARM) {
  int h = blockIdx.x * blockDim.x + threadIdx.x;
  int b = blockIdx.y;
  int c = blockIdx.z;
  float thre = *thre_p;
  float l1 = thre, l2 = 2.f * thre, l3 = 3.f * thre, l4 = 4.f * thre;
  int t0 = c * CHUNK;
  int tw = t0 - WARM;
  if (tw < 0) tw = 0;
  const bf16* xcol = xp + (size_t)b * T * H + h;
  unsigned char* scol = sp + (size_t)b * T * H + h;
  float mem = 0.f;
  for (int t = tw; t < t0; ++t) {  // warmup (state error ~0.25^WARM)
    float xv = __bfloat162float(xcol[(size_t)t * H]);
    mem = DECAY * mem + xv;
    int s = (mem >= l1) + (mem >= l2) + (mem >= l3) + (mem >= l4);
    mem -= (float)s * thre;
  }
  for (int t = t0; t < t0 + CHUNK; ++t) {
    float xv = __bfloat162float(xcol[(size_t)t * H]);
    mem = DECAY * mem + xv;
    int s = (mem >= l1) + (mem >= l2) + (mem >= l3) + (mem >= l4);
    mem -= (float)s * thre;
    scol[(size_t)t * H] = (unsigned char)s;
  }
}

// ---------------------------------------------------------------- launch
extern "C" void kernel_launch(void* const* d_in, const int* in_sizes, int n_in,
                              void* d_out, int out_size, void* d_ws, size_t ws_size,
                              hipStream_t stream) {
  const float* x     = (const float*)d_in[0];
  const float* alpha = (const float*)d_in[1];
  const float* thre  = (const float*)d_in[2];
  const float* w_in  = (const float*)d_in[3];
  const float* b_in  = (const float*)d_in[4];
  const float* w_out = (const float*)d_in[5];
  const float* b_out = (const float*)d_in[6];
  float* out = (float*)d_out;

  const int B = 4, T = 2048, H = 2048;
  const int M = B * T;  // 8192
  const int K = H, N = H;

  char* ws = (char*)d_ws;
  size_t off = 0;
  bf16* xb            = (bf16*)(ws + off);       // 33.5MB
  signed char* spikes = (signed char*)(ws + off);  // alias: xb dead after GEMM1
  off += (size_t)M * K * 2;
  bf16* w_inT   = (bf16*)(ws + off);              off += (size_t)K * N * 2;  // 8.4MB
  signed char* w_q8T = (signed char*)(ws + off);  off += (size_t)K * N;      // 4.2MB
  float* qscale = (float*)(ws + off);             off += (size_t)N * 4;
  float* qinv   = (float*)(ws + off);             off += (size_t)N * 4;
  unsigned int* qmaxbits = (unsigned int*)(ws + off); off += (size_t)N * 4;
  bf16* xp      = (bf16*)(ws + off);              off += (size_t)M * K * 2;  // 33.5MB

  cast_x_k<<<2048, 256, 0, stream>>>((const float4*)x, (ushort4*)xb, M * K / 4);

  dim3 tb(32, 8);
  dim3 tg(N / 32, K / 32);
  transpose_cast_k<<<tg, tb, 0, stream>>>(w_in, w_inT, N);

  hipMemsetAsync(qmaxbits, 0, (size_t)N * 4, stream);
  const int KCH = 128;
  dim3 cg(N / 256, K / KCH);
  colmax_part_k<<<cg, 256, 0, stream>>>(w_out, qmaxbits, N, KCH);
  colmax_fin_k<<<N / 256, 256, 0, stream>>>(qmaxbits, qscale, qinv, N);
  transpose_quant_k<<<tg, tb, 0, stream>>>(w_out, qinv, w_q8T, N, K);

  dim3 gg(M / 256, N / 256);
  gemm1_bf16_k<<<gg, 512, 0, stream>>>(xb, w_inT, xp, b_in, M, N, K);

  const int CHUNK = 64, WARM = 24, NC = T / CHUNK;
  dim3 sg(H / 256, B, NC);
  snn_scan_k<<<sg, 256, 0, stream>>>(xp, (unsigned char*)spikes, thre, T, H, CHUNK, WARM);

  gemm2_i8_k<<<gg, 512, 0, stream>>>(spikes, w_q8T, out, qscale, b_out, x, alpha, M, N, K);
}